// Round 3
// baseline (390.759 us; speedup 1.0000x reference)
//
#include <hip/hip_runtime.h>
#include <math.h>

#define T_DIM 8192
#define D_DIM 7168
#define E_DIM 256
#define N_GROUPS 8
#define TOPK_GROUPS 4
#define TOP_K 8

#define KS 4
#define KSLEN (D_DIM / KS)        // 1792
#define N_TOK 128                 // tokens per GEMM block
#define BK 64                     // k per staging chunk = 8 granules
#define WSCALE 512.0f
#define INV_WSCALE (1.0f / 512.0f)

typedef _Float16 half8 __attribute__((ext_vector_type(8)));
typedef _Float16 half4v __attribute__((ext_vector_type(4)));
typedef float floatx4 __attribute__((ext_vector_type(4)));

// async global->LDS, 16 B per lane; LDS base wave-uniform, global addr per-lane
__device__ __forceinline__ void gld16(void* lds, const void* gsrc) {
    __builtin_amdgcn_global_load_lds(
        (const __attribute__((address_space(1))) void*)gsrc,
        (__attribute__((address_space(3))) void*)lds, 16, 0, 0);
}

// ---------------------------------------------------------------------------
// Kernel 0: split W [D][E] fp32 -> granule-major fp16 hi/lo, scaled x512.
// Output layout: ghi[((g * E + e) * 8) + j] where g = k>>3, j = k&7.
// This is exactly the MFMA A-fragment order, so the GEMM can stage a
// BK=64 x 256e tile as ONE contiguous 32 KB global_load_lds region.
// ---------------------------------------------------------------------------
__global__ __launch_bounds__(256) void wprep_kernel(
    const float* __restrict__ w, _Float16* __restrict__ ghi, _Float16* __restrict__ glo)
{
    __shared__ float tile[64][65];
    const int k0 = blockIdx.x * 64, e0 = blockIdx.y * 64;
    const int tid = threadIdx.x;
    {
        const int kk = tid >> 4, e4 = (tid & 15) * 4;
#pragma unroll
        for (int i = 0; i < 4; i++) {
            const float4 v = *(const float4*)(w + (size_t)(k0 + kk + i * 16) * E_DIM + e0 + e4);
            tile[kk + i * 16][e4 + 0] = v.x;
            tile[kk + i * 16][e4 + 1] = v.y;
            tile[kk + i * 16][e4 + 2] = v.z;
            tile[kk + i * 16][e4 + 3] = v.w;
        }
    }
    __syncthreads();
    {
        const int ee = tid >> 4, kk4 = (tid & 15) * 4;
#pragma unroll
        for (int i = 0; i < 4; i++) {
            const int e = e0 + ee + i * 16;
            half4v hh, ll;
#pragma unroll
            for (int j = 0; j < 4; j++) {
                const float v = tile[kk4 + j][ee + i * 16 + e0 - e0] * WSCALE;
                const _Float16 h = (_Float16)v;
                hh[j] = h;
                ll[j] = (_Float16)(v - (float)h);
            }
            const int k = k0 + kk4;
            const size_t base = ((size_t)(k >> 3) * E_DIM + e) * 8 + (k & 7);
            *(half4v*)(ghi + base) = hh;
            *(half4v*)(glo + base) = ll;
        }
    }
}

// ---------------------------------------------------------------------------
// split x fp32 -> hi/lo fp16 (8 at a time)
// ---------------------------------------------------------------------------
__device__ __forceinline__ void cvt_split8(const float4 v0, const float4 v1,
                                           half8& h, half8& l)
{
    float f[8] = {v0.x, v0.y, v0.z, v0.w, v1.x, v1.y, v1.z, v1.w};
#pragma unroll
    for (int j = 0; j < 8; j++) {
        const _Float16 hh = (_Float16)f[j];
        h[j] = hh;
        l[j] = (_Float16)(f[j] - (float)hh);
    }
}

// ---------------------------------------------------------------------------
// Kernel 1: split-fp16 MFMA GEMM. Block = 256 experts x 128 tokens, 512 thr
// (8 waves: wave = token-half wh x expert-quarter wq, each 64t x 64e).
// K-split KS=4 over blockIdx.x. A staged via global_load_lds (contiguous,
// fragment-ordered). B converted in-register, fragment-ordered in LDS.
// All LDS reads/writes are stride-16B -> conflict-free.
// ---------------------------------------------------------------------------
__global__ __launch_bounds__(512, 2) void gemm_split_kernel(
    const float* __restrict__ x, const _Float16* __restrict__ ghi,
    const _Float16* __restrict__ glo, float* __restrict__ partial)
{
    __shared__ _Float16 Ah[8 * E_DIM * 8];   // 32 KB  [g][e][8]
    __shared__ _Float16 Al[8 * E_DIM * 8];   // 32 KB
    __shared__ _Float16 Bh[8 * N_TOK * 8];   // 16 KB  [g][t][8]
    __shared__ _Float16 Bl[8 * N_TOK * 8];   // 16 KB

    const int s = blockIdx.x;                // K-slice
    const int m = blockIdx.y;                // token tile
    const int tid = threadIdx.x;
    const int wave = tid >> 6, lane = tid & 63;
    const int lm = lane & 15, kq = lane >> 4;
    const int wq = wave & 3;                 // expert quarter (64 e)
    const int wh = wave >> 2;                // token half (64 t)
    const size_t t0 = (size_t)m * N_TOK;
    const int g_base = (s * KSLEN) >> 3;

    // B-staging thread map: t fastest so ds_write banks are spread
    const int bt = tid & 127;                // token 0..127
    const int bgp = tid >> 7;                // granule pair 0..3

    floatx4 acc[4][4];
#pragma unroll
    for (int mt = 0; mt < 4; mt++)
#pragma unroll
        for (int nt = 0; nt < 4; nt++) acc[mt][nt] = (floatx4)0.0f;

    for (int it = 0; it < KSLEN / BK; ++it) {
        const int g0 = g_base + it * 8;

        // ---- A: 2 x 32 KB contiguous async copies (4 insts/wave each) ----
        {
            const _Float16* srch = ghi + (size_t)g0 * (E_DIM * 8);
            const _Float16* srcl = glo + (size_t)g0 * (E_DIM * 8);
#pragma unroll
            for (int i = 0; i < 4; i++) {
                const int chunk = ((wave * 4 + i) * 64) * 8;   // wave-uniform
                gld16(&Ah[chunk], srch + chunk + lane * 8);
                gld16(&Al[chunk], srcl + chunk + lane * 8);
            }
        }
        // ---- B: load 16 fp32, split, write fragment-ordered ----
        {
            const float* xp = x + (t0 + bt) * (size_t)D_DIM + (size_t)g0 * 8 + bgp * 16;
            const float4 v0 = *(const float4*)(xp);
            const float4 v1 = *(const float4*)(xp + 4);
            const float4 v2 = *(const float4*)(xp + 8);
            const float4 v3 = *(const float4*)(xp + 12);
            half8 h0, l0, h1, l1;
            cvt_split8(v0, v1, h0, l0);
            cvt_split8(v2, v3, h1, l1);
            const int b0 = ((bgp * 2 + 0) * N_TOK + bt) * 8;
            const int b1 = ((bgp * 2 + 1) * N_TOK + bt) * 8;
            *(half8*)&Bh[b0] = h0;
            *(half8*)&Bl[b0] = l0;
            *(half8*)&Bh[b1] = h1;
            *(half8*)&Bl[b1] = l1;
        }
        __syncthreads();   // drains vmcnt (global_load_lds) + lgkm

        // ---- compute: 2 MFMA k-steps of 32 (4 granules each) ----
#pragma unroll
        for (int ks = 0; ks < 2; ks++) {
            const int gg = ks * 4 + kq;
            half8 ah[4], al[4];
#pragma unroll
            for (int mt = 0; mt < 4; mt++) {
                const int off = (gg * E_DIM + wq * 64 + mt * 16 + lm) * 8;
                ah[mt] = *(const half8*)&Ah[off];
                al[mt] = *(const half8*)&Al[off];
            }
#pragma unroll
            for (int nt = 0; nt < 4; nt++) {
                const int offb = (gg * N_TOK + wh * 64 + nt * 16 + lm) * 8;
                const half8 bh = *(const half8*)&Bh[offb];
                const half8 bl = *(const half8*)&Bl[offb];
#pragma unroll
                for (int mt = 0; mt < 4; mt++) {
                    acc[mt][nt] = __builtin_amdgcn_mfma_f32_16x16x32_f16(ah[mt], bh, acc[mt][nt], 0, 0, 0);
                    acc[mt][nt] = __builtin_amdgcn_mfma_f32_16x16x32_f16(ah[mt], bl, acc[mt][nt], 0, 0, 0);
                    acc[mt][nt] = __builtin_amdgcn_mfma_f32_16x16x32_f16(al[mt], bh, acc[mt][nt], 0, 0, 0);
                }
            }
        }
        __syncthreads();
    }

    // ---- epilogue: store raw z' partials. C/D: col(token)=lm, row(e)=kq*4+r
    float* pout = partial + (size_t)s * T_DIM * E_DIM;
#pragma unroll
    for (int nt = 0; nt < 4; nt++) {
        const size_t t = t0 + wh * 64 + nt * 16 + lm;
#pragma unroll
        for (int mt = 0; mt < 4; mt++) {
            const int e = wq * 64 + mt * 16 + kq * 4;
            *(floatx4*)(pout + t * E_DIM + e) = acc[mt][nt];
        }
    }
}

// ---------------------------------------------------------------------------
// Kernel 2: per-token routing. One wave per token, no barriers.
// ---------------------------------------------------------------------------
__global__ __launch_bounds__(64) void router_kernel(
    const float* __restrict__ partial, const float* __restrict__ bias,
    float* __restrict__ w_out, float* __restrict__ i_out)
{
    const int t = blockIdx.x;
    const int lane = threadIdx.x;

    __shared__ float sraw[E_DIM];

    float4 zv = make_float4(0.f, 0.f, 0.f, 0.f);
#pragma unroll
    for (int s = 0; s < KS; s++) {
        const float4 p = *(const float4*)(partial + (size_t)s * T_DIM * E_DIM +
                                          (size_t)t * E_DIM + lane * 4);
        zv.x += p.x; zv.y += p.y; zv.z += p.z; zv.w += p.w;
    }
    float4 sv;
    sv.x = 1.0f / (1.0f + expf(-zv.x * INV_WSCALE));
    sv.y = 1.0f / (1.0f + expf(-zv.y * INV_WSCALE));
    sv.z = 1.0f / (1.0f + expf(-zv.z * INV_WSCALE));
    sv.w = 1.0f / (1.0f + expf(-zv.w * INV_WSCALE));

    const float4 bz = *(const float4*)(bias + lane * 4);
    *(float4*)(&sraw[lane * 4]) = sv;   // single wave: no barrier needed

    float sb[4];
    sb[0] = sv.x + bz.x; sb[1] = sv.y + bz.y; sb[2] = sv.z + bz.z; sb[3] = sv.w + bz.w;

    // group top-2 sum (8 lanes per group)
    float m1 = -INFINITY, m2 = -INFINITY;
#pragma unroll
    for (int j = 0; j < 4; j++) {
        const float v = sb[j];
        if (v > m1) { m2 = m1; m1 = v; }
        else if (v > m2) { m2 = v; }
    }
#pragma unroll
    for (int d = 1; d < 8; d <<= 1) {
        const float o1 = __shfl_xor(m1, d);
        const float o2 = __shfl_xor(m2, d);
        const float hi = fmaxf(m1, o1);
        const float lo = fminf(m1, o1);
        m2 = fmaxf(lo, fmaxf(m2, o2));
        m1 = hi;
    }
    const float gscore = m1 + m2;

    float gs[N_GROUPS];
#pragma unroll
    for (int g = 0; g < N_GROUPS; g++) gs[g] = __shfl(gscore, g * 8);

    unsigned gmask = 0u;
#pragma unroll
    for (int r = 0; r < TOPK_GROUPS; r++) {
        int best = 0; float bv = -INFINITY;
#pragma unroll
        for (int g = 0; g < N_GROUPS; g++) {
            const bool taken = (gmask >> g) & 1u;
            if (!taken && gs[g] > bv) { bv = gs[g]; best = g; }
        }
        gmask |= (1u << best);
    }

    const int myg = lane >> 3;
    const float keep = ((gmask >> myg) & 1u) ? 1.0f : 0.0f;
    float v[4];
#pragma unroll
    for (int j = 0; j < 4; j++) v[j] = keep * sb[j];

    int selIdx[TOP_K];
#pragma unroll
    for (int it = 0; it < TOP_K; it++) {
        float bv = -INFINITY; int bi = E_DIM;
#pragma unroll
        for (int j = 0; j < 4; j++) {
            if (v[j] > bv) { bv = v[j]; bi = 4 * lane + j; }
        }
#pragma unroll
        for (int off = 32; off > 0; off >>= 1) {
            const float ov = __shfl_down(bv, off);
            const int   oi = __shfl_down(bi, off);
            if (ov > bv || (ov == bv && oi < bi)) { bv = ov; bi = oi; }
        }
        bi = __shfl(bi, 0);
        selIdx[it] = bi;
        if (lane == (bi >> 2)) v[bi & 3] = -INFINITY;
    }

    float wv[TOP_K];
    float wsum = 0.0f;
#pragma unroll
    for (int it = 0; it < TOP_K; it++) {
        wv[it] = sraw[selIdx[it]];
        wsum += wv[it];
    }
    const float inv = 2.5f / (wsum + 1e-20f);

#pragma unroll
    for (int it = 0; it < TOP_K; it++) {
        if (lane == it) {
            w_out[(size_t)t * TOP_K + it] = wv[it] * inv;
            i_out[(size_t)t * TOP_K + it] = (float)selIdx[it];
        }
    }
}

// ---------------------------------------------------------------------------
extern "C" void kernel_launch(void* const* d_in, const int* in_sizes, int n_in,
                              void* d_out, int out_size, void* d_ws, size_t ws_size,
                              hipStream_t stream) {
    const float* x    = (const float*)d_in[0];
    const float* w    = (const float*)d_in[1];
    const float* bias = (const float*)d_in[2];

    float* w_out = (float*)d_out;
    float* i_out = w_out + (size_t)T_DIM * TOP_K;

    const size_t PART = (size_t)T_DIM * E_DIM * sizeof(float);     // 8.39 MB
    float*    partial = (float*)d_ws;
    _Float16* ghi     = (_Float16*)((char*)d_ws + (size_t)KS * PART);
    _Float16* glo     = ghi + (size_t)E_DIM * D_DIM;

    wprep_kernel<<<dim3(D_DIM / 64, E_DIM / 64), 256, 0, stream>>>(w, ghi, glo);
    gemm_split_kernel<<<dim3(KS, T_DIM / N_TOK), 512, 0, stream>>>(x, ghi, glo, partial);
    router_kernel<<<T_DIM, 64, 0, stream>>>(partial, bias, w_out, i_out);
}